// Round 5
// baseline (409.667 us; speedup 1.0000x reference)
//
#include <hip/hip_runtime.h>

typedef unsigned short u16;
typedef __bf16 bf16x8 __attribute__((ext_vector_type(8)));
typedef float f32x4 __attribute__((ext_vector_type(4)));

// Problem constants: B=2, S=2048, D=2048, H=16, HD=128, F=3*H*HD=6144, M=B*S=4096

__device__ __forceinline__ u16 f2bf(float x) {
  __bf16 h = (__bf16)x;
  return __builtin_bit_cast(u16, h);
}

// async global->LDS, 16B per lane. LDS dest must be wave-uniform; HW scatters lane i to base+16*i.
__device__ __forceinline__ void async_copy16(void* lds, const void* g) {
  __builtin_amdgcn_global_load_lds((const __attribute__((address_space(1))) void*)g,
                                   (__attribute__((address_space(3))) void*)lds, 16, 0, 0);
}

// ---------------- fused cast fp32 -> bf16 for all three tensors ----------------
__global__ __launch_bounds__(256) void cast_all(const float* __restrict__ hidden,
                                                const float* __restrict__ wqkv,
                                                const float* __restrict__ wo,
                                                u16* __restrict__ xb,
                                                u16* __restrict__ wqb,
                                                u16* __restrict__ wob) {
  int i = blockIdx.x * 256 + threadIdx.x;  // 6291456 vec4 total
  const float* s;
  u16* d;
  int off;
  if (i < 2097152) { s = hidden; d = xb; off = i; }
  else if (i < 2097152 + 3145728) { s = wqkv; d = wqb; off = i - 2097152; }
  else { s = wo; d = wob; off = i - (2097152 + 3145728); }
  float4 v = ((const float4*)s)[off];
  ushort4 o;
  o.x = f2bf(v.x); o.y = f2bf(v.y); o.z = f2bf(v.z); o.w = f2bf(v.w);
  ((ushort4*)d)[off] = o;
}

// ---------------- QKV projection GEMM + fused RoPE (+ softmax scale folded into Q) ----
// C[m,f] = sum_d X[m,d] * W[f,d]. M=4096, N=6144, K=2048. Tile 128x128, BK=64.
// Wave n-tile -> column mapping puts rope pairs (hd, hd+64) in the SAME lane:
//   col(n) = (wave&1)*32 + (n&1)*16 + (n>>1)*64 + r16   (n=0..3; col(n+2)=col(n)+64)
// Q additionally scaled by 1/sqrt(HD)*log2(e) so flash uses exp2 directly.
__global__ __launch_bounds__(256) void gemm_qkv(const u16* __restrict__ A,
                                                const u16* __restrict__ W,
                                                const float* __restrict__ cosb,
                                                const float* __restrict__ sinb,
                                                u16* __restrict__ Qb,
                                                u16* __restrict__ Kb,
                                                u16* __restrict__ Vt) {
  __shared__ __align__(16) u16 As[128 * 64];
  __shared__ __align__(16) u16 Bs[128 * 64];
  const int tid = threadIdx.x;
  const int lane = tid & 63;
  const int wave = tid >> 6;
  const int wm = (wave >> 1) * 64;
  const int r16 = lane & 15;
  const int g4 = lane >> 4;
  const int rsw = r16 & 7;
  const int bm = blockIdx.x * 128;
  const int bn = blockIdx.y * 128;

  // staging map (constant over k): issue i covers rows wave*32+i*8 .. +7
  size_t aoff[4], boff[4];
  u16* ldsA[4];
  u16* ldsB[4];
#pragma unroll
  for (int i = 0; i < 4; i++) {
    int row = wave * 32 + i * 8 + (lane >> 3);
    int c = (lane & 7) ^ (row & 7);  // global chunk feeding this lane's LDS slot
    aoff[i] = (size_t)(bm + row) * 2048 + c * 8;
    boff[i] = (size_t)(bn + row) * 2048 + c * 8;
    ldsA[i] = &As[(wave * 4 + i) * 512];
    ldsB[i] = &Bs[(wave * 4 + i) * 512];
  }

  int bcol[4];
#pragma unroll
  for (int n = 0; n < 4; n++) bcol[n] = (wave & 1) * 32 + (n & 1) * 16 + (n >> 1) * 64;

  f32x4 acc[4][4];
  f32x4 zero = {0.0f, 0.0f, 0.0f, 0.0f};
#pragma unroll
  for (int m = 0; m < 4; m++)
#pragma unroll
    for (int n = 0; n < 4; n++) acc[m][n] = zero;

  for (int kt = 0; kt < 2048; kt += 64) {
    __syncthreads();
#pragma unroll
    for (int i = 0; i < 4; i++) {
      async_copy16(ldsA[i], A + aoff[i] + kt);
      async_copy16(ldsB[i], W + boff[i] + kt);
    }
    __syncthreads();
#pragma unroll
    for (int ks = 0; ks < 2; ks++) {
      bf16x8 af[4], bfr[4];
#pragma unroll
      for (int m = 0; m < 4; m++)
        af[m] = *(const bf16x8*)(&As[(wm + m * 16 + r16) * 64 + ((ks * 4 + g4) ^ rsw) * 8]);
#pragma unroll
      for (int n = 0; n < 4; n++)
        bfr[n] = *(const bf16x8*)(&Bs[(bcol[n] + r16) * 64 + ((ks * 4 + g4) ^ rsw) * 8]);
#pragma unroll
      for (int m = 0; m < 4; m++)
#pragma unroll
        for (int n = 0; n < 4; n++)
          acc[m][n] = __builtin_amdgcn_mfma_f32_16x16x32_bf16(af[m], bfr[n], acc[m][n], 0, 0, 0);
    }
  }

  const int which = blockIdx.y % 3;
  const int hh = blockIdx.y / 3;
  // Q gets 1/sqrt(128)*log2(e) folded in so flash's softmax is pure exp2
  const float qs = (which == 0) ? 0.08838834764831845f * 1.4426950408889634f : 1.0f;
#pragma unroll
  for (int m = 0; m < 4; m++) {
#pragma unroll
    for (int r = 0; r < 4; r++) {
      // C/D layout (m89): col = lane&15, row = (lane>>4)*4 + r
      int row = bm + wm + m * 16 + g4 * 4 + r;  // global m index (b*S+s)
      int bb = row >> 11;
      int s = row & 2047;
      size_t bhIdx = (size_t)(bb * 16 + hh);
      if (which == 2) {
#pragma unroll
        for (int n = 0; n < 4; n++) {
          int hd = bcol[n] + r16;
          Vt[(bhIdx * 128 + hd) * 2048 + s] = f2bf(acc[m][n][r]);  // V^T: [bh][hd][s]
        }
      } else {
        u16* dst = (which ? Kb : Qb) + (bhIdx * 2048 + s) * 128;
#pragma unroll
        for (int n = 0; n < 2; n++) {
          int hd = bcol[n] + r16;  // < 64; pair is hd+64 in acc[m][n+2]
          float c = cosb[s * 128 + hd] * qs;
          float sn = sinb[s * 128 + hd] * qs;
          float x1 = acc[m][n][r], x2 = acc[m][n + 2][r];
          dst[hd] = f2bf(x1 * c - x2 * sn);
          dst[hd + 64] = f2bf(x2 * c + x1 * sn);
        }
      }
    }
  }
}

// ---------------- Flash attention (causal, online softmax, S^T + O^T, 128-key tiles) --
// Grid (16, B*H). Block x processes q-tiles t=x and t=31-x; nk(t)=t/2+1 key-tiles of 128
// -> uniform 17 iterations per block (vs 33 with 64-key tiles): the serial per-iteration
// skeleton (barrier + softmax chain + P round-trip) traverses half as often.
// K [128kx128hd] and V^T [128hdx128k] single-buffered via global_load_lds (XOR-swizzled);
// P round-trips through the per-wave stride-72 Ps buffer in two 64-key halves.
// S^T = mfma(K,Q), O^T = mfma(V^T,P): softmax state and rescale fully lane-local.
__global__ __launch_bounds__(256) void flash_attn(const u16* __restrict__ Q,
                                                  const u16* __restrict__ K,
                                                  const u16* __restrict__ Vt,
                                                  u16* __restrict__ O) {
  __shared__ __align__(16) u16 Ks[128 * 128];    // [key][hd], 16B chunks XOR-swizzled
  __shared__ __align__(16) u16 Vs[128 * 128];    // [hd][key], 16B chunks XOR-swizzled
  __shared__ __align__(16) u16 Ps[4 * 16 * 72];  // per-wave [q][64 keys], padded
  const int tid = threadIdx.x;
  const int lane = tid & 63;
  const int wave = tid >> 6;
  const int bh = blockIdx.y;
  const int r16 = lane & 15;
  const int g4 = lane >> 4;
  const int rsw = r16 & 7;
  const u16* Qh = Q + (size_t)bh * 2048 * 128;
  const u16* Kh = K + (size_t)bh * 2048 * 128;
  const u16* Vh = Vt + (size_t)bh * 128 * 2048;
  const int b = bh >> 4;
  const int h = bh & 15;

  // staging maps: 8 issues each for K and V; issue i covers rows (wave*8+i)*4 + (lane>>4)
  int koff[8], voff[8], ldsOff[8];
#pragma unroll
  for (int i = 0; i < 8; i++) {
    int r = (wave * 8 + i) * 4 + (lane >> 4);  // 0..127
    int c = (lane & 15) ^ (r & 7);             // global chunk feeding this lane's LDS slot
    koff[i] = r * 128 + c * 8;                 // K: [key r][hd], +u*16384 at use
    voff[i] = r * 2048 + c * 8;                // V^T: [hd r][s], +u*128 at use
    ldsOff[i] = (wave * 8 + i) * 512;          // 4 rows x 128 elems
  }

#pragma unroll 1
  for (int pass = 0; pass < 2; pass++) {
    const int t = pass == 0 ? (int)blockIdx.x : 31 - (int)blockIdx.x;
    const int qg = t * 64 + wave * 16 + r16;  // this lane's query row
    const int nk = t / 2 + 1;                 // # of 128-key tiles

    // Q fragments (B-operand of S^T; lane layout: q=lane&15, k=(lane>>4)*8+j)
    bf16x8 qf[4];
#pragma unroll
    for (int ks = 0; ks < 4; ks++)
      qf[ks] = *(const bf16x8*)(Qh + (size_t)qg * 128 + ks * 32 + g4 * 8);

    f32x4 o[8];  // O^T: tile c = hd 16c..16c+15; col=q=r16, row=hd=g4*4+r
    f32x4 zero = {0.0f, 0.0f, 0.0f, 0.0f};
#pragma unroll
    for (int c = 0; c < 8; c++) o[c] = zero;
    float m_i = -__builtin_inff();
    float l_i = 0.0f;

    for (int u = 0; u < nk; u++) {
      __syncthreads();  // all waves done reading previous tile
#pragma unroll
      for (int i = 0; i < 8; i++) {
        async_copy16(&Ks[ldsOff[i]], Kh + (size_t)u * 16384 + koff[i]);
        async_copy16(&Vs[ldsOff[i]], Vh + (size_t)u * 128 + voff[i]);
      }
      __syncthreads();  // staging drained

      // S^T = K Q^T : tile n covers keys u*128 + 16n .. +15
      f32x4 sacc[8];
#pragma unroll
      for (int n = 0; n < 8; n++) sacc[n] = zero;
#pragma unroll
      for (int n = 0; n < 8; n++) {
#pragma unroll
        for (int ks = 0; ks < 4; ks++) {
          bf16x8 kf = *(const bf16x8*)(&Ks[(n * 16 + r16) * 128 + ((ks * 4 + g4) ^ rsw) * 8]);
          sacc[n] = __builtin_amdgcn_mfma_f32_16x16x32_bf16(kf, qf[ks], sacc[n], 0, 0, 0);
        }
      }

      // causal mask (only possible in the last tile; uniform branch) + running max
      if (u == nk - 1) {
#pragma unroll
        for (int n = 0; n < 8; n++)
#pragma unroll
          for (int r = 0; r < 4; r++) {
            int key = u * 128 + 16 * n + g4 * 4 + r;
            if (key > qg) sacc[n][r] = -__builtin_inff();
          }
      }
      float vmax = -__builtin_inff();
#pragma unroll
      for (int n = 0; n < 8; n++)
#pragma unroll
        for (int r = 0; r < 4; r++) vmax = fmaxf(vmax, sacc[n][r]);
      vmax = fmaxf(vmax, __shfl_xor(vmax, 16));
      vmax = fmaxf(vmax, __shfl_xor(vmax, 32));
      float mn = fmaxf(m_i, vmax);
      float alpha = exp2f(m_i - mn);
      m_i = mn;

      // O^T rescale BEFORE accumulating this tile (col = q = lane-local alpha)
#pragma unroll
      for (int c = 0; c < 8; c++)
#pragma unroll
        for (int r = 0; r < 4; r++) o[c][r] *= alpha;

      float ssum = 0.0f;
      u16* Pw = &Ps[wave * 16 * 72];
#pragma unroll
      for (int half = 0; half < 2; half++) {
        // exp + pack + write this half's 64 keys into the per-wave P buffer
#pragma unroll
        for (int nl = 0; nl < 4; nl++) {
          int n = half * 4 + nl;
          float p0 = exp2f(sacc[n][0] - mn);
          float p1 = exp2f(sacc[n][1] - mn);
          float p2 = exp2f(sacc[n][2] - mn);
          float p3 = exp2f(sacc[n][3] - mn);
          ssum += (p0 + p1) + (p2 + p3);
          ushort4 pk;
          pk.x = f2bf(p0); pk.y = f2bf(p1); pk.z = f2bf(p2); pk.w = f2bf(p3);
          *(ushort4*)(&Pw[r16 * 72 + 16 * nl + g4 * 4]) = pk;  // P[q][local key]
        }
        // O^T += V^T * P for this half's keys (global k-steps 2*half, 2*half+1)
#pragma unroll
        for (int ks2 = 0; ks2 < 2; ks2++) {
          bf16x8 pf = *(const bf16x8*)(&Pw[r16 * 72 + ks2 * 32 + g4 * 8]);
          int kv = half * 2 + ks2;
#pragma unroll
          for (int c = 0; c < 8; c++) {
            bf16x8 vf = *(const bf16x8*)(&Vs[(c * 16 + r16) * 128 + ((kv * 4 + g4) ^ rsw) * 8]);
            o[c] = __builtin_amdgcn_mfma_f32_16x16x32_bf16(vf, pf, o[c], 0, 0, 0);
          }
        }
      }
      ssum += __shfl_xor(ssum, 16);
      ssum += __shfl_xor(ssum, 32);
      l_i = l_i * alpha + ssum;
    }

    // epilogue: O^T /= l (lane-local), write [B,S,H,HD] bf16 as packed 8B stores
    float rl = 1.0f / l_i;
    u16* dst = O + ((size_t)(b * 2048 + qg)) * 2048 + h * 128;
#pragma unroll
    for (int c = 0; c < 8; c++) {
      ushort4 pk;
      pk.x = f2bf(o[c][0] * rl);
      pk.y = f2bf(o[c][1] * rl);
      pk.z = f2bf(o[c][2] * rl);
      pk.w = f2bf(o[c][3] * rl);
      *(ushort4*)(dst + c * 16 + g4 * 4) = pk;
    }
  }
}

// ---------------- Output projection GEMM ----------------
// out[m,d] = sum_f Attn[m,f] * Wo[d,f]. M=4096, N=2048, K=2048. fp32 output.
__global__ __launch_bounds__(256) void gemm_out(const u16* __restrict__ A,
                                                const u16* __restrict__ W,
                                                float* __restrict__ out) {
  __shared__ __align__(16) u16 As[128 * 64];
  __shared__ __align__(16) u16 Bs[128 * 64];
  const int tid = threadIdx.x;
  const int lane = tid & 63;
  const int wave = tid >> 6;
  const int wm = (wave >> 1) * 64;
  const int wn = (wave & 1) * 64;
  const int r16 = lane & 15;
  const int g4 = lane >> 4;
  const int rsw = r16 & 7;
  const int bm = blockIdx.x * 128;
  const int bn = blockIdx.y * 128;

  size_t aoff[4], boff[4];
  u16* ldsA[4];
  u16* ldsB[4];
#pragma unroll
  for (int i = 0; i < 4; i++) {
    int row = wave * 32 + i * 8 + (lane >> 3);
    int c = (lane & 7) ^ (row & 7);
    aoff[i] = (size_t)(bm + row) * 2048 + c * 8;
    boff[i] = (size_t)(bn + row) * 2048 + c * 8;
    ldsA[i] = &As[(wave * 4 + i) * 512];
    ldsB[i] = &Bs[(wave * 4 + i) * 512];
  }

  f32x4 acc[4][4];
  f32x4 zero = {0.0f, 0.0f, 0.0f, 0.0f};
#pragma unroll
  for (int m = 0; m < 4; m++)
#pragma unroll
    for (int n = 0; n < 4; n++) acc[m][n] = zero;

  for (int kt = 0; kt < 2048; kt += 64) {
    __syncthreads();
#pragma unroll
    for (int i = 0; i < 4; i++) {
      async_copy16(ldsA[i], A + aoff[i] + kt);
      async_copy16(ldsB[i], W + boff[i] + kt);
    }
    __syncthreads();
#pragma unroll
    for (int ks = 0; ks < 2; ks++) {
      bf16x8 af[4], bfr[4];
#pragma unroll
      for (int m = 0; m < 4; m++)
        af[m] = *(const bf16x8*)(&As[(wm + m * 16 + r16) * 64 + ((ks * 4 + g4) ^ rsw) * 8]);
#pragma unroll
      for (int n = 0; n < 4; n++)
        bfr[n] = *(const bf16x8*)(&Bs[(wn + n * 16 + r16) * 64 + ((ks * 4 + g4) ^ rsw) * 8]);
#pragma unroll
      for (int m = 0; m < 4; m++)
#pragma unroll
        for (int n = 0; n < 4; n++)
          acc[m][n] = __builtin_amdgcn_mfma_f32_16x16x32_bf16(af[m], bfr[n], acc[m][n], 0, 0, 0);
    }
  }

#pragma unroll
  for (int m = 0; m < 4; m++) {
#pragma unroll
    for (int n = 0; n < 4; n++) {
#pragma unroll
      for (int r = 0; r < 4; r++) {
        int row = bm + wm + m * 16 + g4 * 4 + r;
        int col = bn + wn + n * 16 + r16;
        out[(size_t)row * 2048 + col] = acc[m][n][r];
      }
    }
  }
}

extern "C" void kernel_launch(void* const* d_in, const int* in_sizes, int n_in,
                              void* d_out, int out_size, void* d_ws, size_t ws_size,
                              hipStream_t stream) {
  const float* hidden = (const float*)d_in[0];  // [2,2048,2048]
  const float* cosb   = (const float*)d_in[1];  // [2048,128]
  const float* sinb   = (const float*)d_in[2];  // [2048,128]
  const float* w_qkv  = (const float*)d_in[3];  // [3,2048,2048] -> flat [6144,2048]
  const float* w_o    = (const float*)d_in[4];  // [2048,2048]
  float* out = (float*)d_out;                   // [2,2048,2048] fp32

  char* ws = (char*)d_ws;
  u16* Xbf    = (u16*)(ws);                 // 16 MiB
  u16* Wqkvbf = (u16*)(ws + 16777216);      // 24 MiB
  u16* Wobf   = (u16*)(ws + 41943040);      // 8 MiB
  u16* Qb     = (u16*)(ws + 50331648);      // [B,H,S,HD] 16 MiB
  u16* Kb     = (u16*)(ws + 67108864);      // [B,H,S,HD] 16 MiB
  u16* Vt     = (u16*)(ws + 83886080);      // [B,H,HD,S] 16 MiB
  u16* Ob     = (u16*)(ws + 100663296);     // [B,S,H,HD] 16 MiB (end 112 MiB)

  cast_all<<<24576, 256, 0, stream>>>(hidden, w_qkv, w_o, Xbf, Wqkvbf, Wobf);
  gemm_qkv<<<dim3(32, 48), 256, 0, stream>>>(Xbf, Wqkvbf, cosb, sinb, Qb, Kb, Vt);
  flash_attn<<<dim3(16, 32), 256, 0, stream>>>(Qb, Kb, Vt, Ob);
  gemm_out<<<dim3(32, 16), 256, 0, stream>>>(Ob, Wobf, out);
}

// Round 6
// 396.392 us; speedup vs baseline: 1.0335x; 1.0335x over previous
//
#include <hip/hip_runtime.h>

typedef unsigned short u16;
typedef __bf16 bf16x8 __attribute__((ext_vector_type(8)));
typedef float f32x4 __attribute__((ext_vector_type(4)));

// Problem constants: B=2, S=2048, D=2048, H=16, HD=128, F=3*H*HD=6144, M=B*S=4096

__device__ __forceinline__ u16 f2bf(float x) {
  __bf16 h = (__bf16)x;
  return __builtin_bit_cast(u16, h);
}

// async global->LDS, 16B per lane. LDS dest must be wave-uniform; HW scatters lane i to base+16*i.
__device__ __forceinline__ void async_copy16(void* lds, const void* g) {
  __builtin_amdgcn_global_load_lds((const __attribute__((address_space(1))) void*)g,
                                   (__attribute__((address_space(3))) void*)lds, 16, 0, 0);
}

// ---------------- fused cast fp32 -> bf16 for all three tensors ----------------
__global__ __launch_bounds__(256) void cast_all(const float* __restrict__ hidden,
                                                const float* __restrict__ wqkv,
                                                const float* __restrict__ wo,
                                                u16* __restrict__ xb,
                                                u16* __restrict__ wqb,
                                                u16* __restrict__ wob) {
  int i = blockIdx.x * 256 + threadIdx.x;  // 6291456 vec4 total
  const float* s;
  u16* d;
  int off;
  if (i < 2097152) { s = hidden; d = xb; off = i; }
  else if (i < 2097152 + 3145728) { s = wqkv; d = wqb; off = i - 2097152; }
  else { s = wo; d = wob; off = i - (2097152 + 3145728); }
  float4 v = ((const float4*)s)[off];
  ushort4 o;
  o.x = f2bf(v.x); o.y = f2bf(v.y); o.z = f2bf(v.z); o.w = f2bf(v.w);
  ((ushort4*)d)[off] = o;
}

// ---------------- QKV projection GEMM + fused RoPE (+ softmax scale folded into Q) ----
// C[m,f] = sum_d X[m,d] * W[f,d]. M=4096, N=6144, K=2048. Tile 128x128, BK=64.
// Wave n-tile -> column mapping puts rope pairs (hd, hd+64) in the SAME lane:
//   col(n) = (wave&1)*32 + (n&1)*16 + (n>>1)*64 + r16   (n=0..3; col(n+2)=col(n)+64)
// Q additionally scaled by 1/sqrt(HD)*log2(e) so flash uses exp2 directly.
__global__ __launch_bounds__(256) void gemm_qkv(const u16* __restrict__ A,
                                                const u16* __restrict__ W,
                                                const float* __restrict__ cosb,
                                                const float* __restrict__ sinb,
                                                u16* __restrict__ Qb,
                                                u16* __restrict__ Kb,
                                                u16* __restrict__ Vt) {
  __shared__ __align__(16) u16 As[128 * 64];
  __shared__ __align__(16) u16 Bs[128 * 64];
  const int tid = threadIdx.x;
  const int lane = tid & 63;
  const int wave = tid >> 6;
  const int wm = (wave >> 1) * 64;
  const int r16 = lane & 15;
  const int g4 = lane >> 4;
  const int rsw = r16 & 7;
  const int bm = blockIdx.x * 128;
  const int bn = blockIdx.y * 128;

  // staging map (constant over k): issue i covers rows wave*32+i*8 .. +7
  size_t aoff[4], boff[4];
  u16* ldsA[4];
  u16* ldsB[4];
#pragma unroll
  for (int i = 0; i < 4; i++) {
    int row = wave * 32 + i * 8 + (lane >> 3);
    int c = (lane & 7) ^ (row & 7);  // global chunk feeding this lane's LDS slot
    aoff[i] = (size_t)(bm + row) * 2048 + c * 8;
    boff[i] = (size_t)(bn + row) * 2048 + c * 8;
    ldsA[i] = &As[(wave * 4 + i) * 512];
    ldsB[i] = &Bs[(wave * 4 + i) * 512];
  }

  int bcol[4];
#pragma unroll
  for (int n = 0; n < 4; n++) bcol[n] = (wave & 1) * 32 + (n & 1) * 16 + (n >> 1) * 64;

  f32x4 acc[4][4];
  f32x4 zero = {0.0f, 0.0f, 0.0f, 0.0f};
#pragma unroll
  for (int m = 0; m < 4; m++)
#pragma unroll
    for (int n = 0; n < 4; n++) acc[m][n] = zero;

  for (int kt = 0; kt < 2048; kt += 64) {
    __syncthreads();
#pragma unroll
    for (int i = 0; i < 4; i++) {
      async_copy16(ldsA[i], A + aoff[i] + kt);
      async_copy16(ldsB[i], W + boff[i] + kt);
    }
    __syncthreads();
#pragma unroll
    for (int ks = 0; ks < 2; ks++) {
      bf16x8 af[4], bfr[4];
#pragma unroll
      for (int m = 0; m < 4; m++)
        af[m] = *(const bf16x8*)(&As[(wm + m * 16 + r16) * 64 + ((ks * 4 + g4) ^ rsw) * 8]);
#pragma unroll
      for (int n = 0; n < 4; n++)
        bfr[n] = *(const bf16x8*)(&Bs[(bcol[n] + r16) * 64 + ((ks * 4 + g4) ^ rsw) * 8]);
#pragma unroll
      for (int m = 0; m < 4; m++)
#pragma unroll
        for (int n = 0; n < 4; n++)
          acc[m][n] = __builtin_amdgcn_mfma_f32_16x16x32_bf16(af[m], bfr[n], acc[m][n], 0, 0, 0);
    }
  }

  const int which = blockIdx.y % 3;
  const int hh = blockIdx.y / 3;
  // Q gets 1/sqrt(128)*log2(e) folded in so flash's softmax is pure exp2
  const float qs = (which == 0) ? 0.08838834764831845f * 1.4426950408889634f : 1.0f;
#pragma unroll
  for (int m = 0; m < 4; m++) {
#pragma unroll
    for (int r = 0; r < 4; r++) {
      // C/D layout (m89): col = lane&15, row = (lane>>4)*4 + r
      int row = bm + wm + m * 16 + g4 * 4 + r;  // global m index (b*S+s)
      int bb = row >> 11;
      int s = row & 2047;
      size_t bhIdx = (size_t)(bb * 16 + hh);
      if (which == 2) {
#pragma unroll
        for (int n = 0; n < 4; n++) {
          int hd = bcol[n] + r16;
          Vt[(bhIdx * 128 + hd) * 2048 + s] = f2bf(acc[m][n][r]);  // V^T: [bh][hd][s]
        }
      } else {
        u16* dst = (which ? Kb : Qb) + (bhIdx * 2048 + s) * 128;
#pragma unroll
        for (int n = 0; n < 2; n++) {
          int hd = bcol[n] + r16;  // < 64; pair is hd+64 in acc[m][n+2]
          float c = cosb[s * 128 + hd] * qs;
          float sn = sinb[s * 128 + hd] * qs;
          float x1 = acc[m][n][r], x2 = acc[m][n + 2][r];
          dst[hd] = f2bf(x1 * c - x2 * sn);
          dst[hd + 64] = f2bf(x2 * c + x1 * sn);
        }
      }
    }
  }
}

// ---------------- Flash attention: 128-query x 128-key tiles, 512 threads --------------
// Grid (8, B*H). Block x processes q-tiles T=x and T=15-x (128 q-rows each);
// nk(T)=T+1 key-tiles -> uniform 17 iterations per block. K/V staged bytes per unit
// output HALVE vs the 64-q version (each staged tile serves 128 queries) — this is the
// lever for the L3-bandwidth-bound staging stream (~556 MB -> ~278 MB).
// K [128k x 128hd] and V^T [128hd x 128k] double-buffered via global_load_lds
// (16B-chunk XOR swizzle); prefetch for u+1 issued right after the single barrier.
// S^T = mfma(K,Q): lane owns scores of query q=lane&15; O^T = mfma(V^T,P): col=q —
// softmax state and rescale fully lane-local. P round-trips per-wave LDS (swizzled).
__global__ __launch_bounds__(512) void flash_attn(const u16* __restrict__ Q,
                                                  const u16* __restrict__ K,
                                                  const u16* __restrict__ Vt,
                                                  u16* __restrict__ O) {
  __shared__ __align__(16) u16 Ks[2][128 * 128];
  __shared__ __align__(16) u16 Vs[2][128 * 128];
  __shared__ __align__(16) u16 Ps[8 * 16 * 64];  // per-wave [q][64 keys], XOR-swizzled
  const int tid = threadIdx.x;
  const int lane = tid & 63;
  const int wave = tid >> 6;  // 0..7
  const int bh = blockIdx.y;
  const int r16 = lane & 15;
  const int g4 = lane >> 4;
  const int rsw = r16 & 7;
  const u16* Qh = Q + (size_t)bh * 2048 * 128;
  const u16* Kh = K + (size_t)bh * 2048 * 128;
  const u16* Vh = Vt + (size_t)bh * 128 * 2048;
  const int b = bh >> 4;
  const int h = bh & 15;

  // staging maps: K and V^T tiles are both 128 rows x 16 chunks; 4 issues per wave each.
  int koff[4], voff[4], ldsOff[4];
#pragma unroll
  for (int i = 0; i < 4; i++) {
    int r = (wave * 4 + i) * 4 + (lane >> 4);  // 0..127
    int c = (lane & 15) ^ (r & 7);             // global chunk feeding this lane's LDS slot
    koff[i] = r * 128 + c * 8;                 // K: [key r][hd], +u*16384 at use
    voff[i] = r * 2048 + c * 8;                // V^T: [hd r][s], +u*128 at use
    ldsOff[i] = (wave * 4 + i) * 512;          // 4 rows x 128 elems
  }

#pragma unroll 1
  for (int pass = 0; pass < 2; pass++) {
    const int T = pass == 0 ? (int)blockIdx.x : 15 - (int)blockIdx.x;
    const int qg = T * 128 + wave * 16 + r16;  // this lane's query row
    const int nk = T + 1;                      // # of 128-key tiles

    // Q fragments (B-operand of S^T; lane layout: q=lane&15, k=(lane>>4)*8+j)
    bf16x8 qf[4];
#pragma unroll
    for (int ks = 0; ks < 4; ks++)
      qf[ks] = *(const bf16x8*)(Qh + (size_t)qg * 128 + ks * 32 + g4 * 8);

    f32x4 o[8];  // O^T: tile c = hd 16c..16c+15; col=q=r16, row=hd=g4*4+r
    f32x4 zero = {0.0f, 0.0f, 0.0f, 0.0f};
#pragma unroll
    for (int c = 0; c < 8; c++) o[c] = zero;
    float m_i = -__builtin_inff();
    float l_i = 0.0f;

    __syncthreads();  // previous pass done with all buffers before restaging
#pragma unroll
    for (int i = 0; i < 4; i++) {  // prologue: stage u=0 into buf 0
      async_copy16(&Ks[0][ldsOff[i]], Kh + koff[i]);
      async_copy16(&Vs[0][ldsOff[i]], Vh + voff[i]);
    }

    int cur = 0;
    for (int u = 0; u < nk; u++) {
      __syncthreads();   // drains staging of buf[cur]; all waves done with buf[cur^1]
      if (u + 1 < nk) {  // prefetch u+1; in flight across the whole compute section
#pragma unroll
        for (int i = 0; i < 4; i++) {
          async_copy16(&Ks[cur ^ 1][ldsOff[i]], Kh + (size_t)(u + 1) * 16384 + koff[i]);
          async_copy16(&Vs[cur ^ 1][ldsOff[i]], Vh + (size_t)(u + 1) * 128 + voff[i]);
        }
      }

      // S^T = K Q^T : tile n covers keys u*128 + 16n .. +15
      f32x4 sacc[8];
#pragma unroll
      for (int n = 0; n < 8; n++) sacc[n] = zero;
#pragma unroll
      for (int n = 0; n < 8; n++) {
#pragma unroll
        for (int ks = 0; ks < 4; ks++) {
          bf16x8 kf = *(const bf16x8*)(&Ks[cur][(n * 16 + r16) * 128 + ((ks * 4 + g4) ^ rsw) * 8]);
          sacc[n] = __builtin_amdgcn_mfma_f32_16x16x32_bf16(kf, qf[ks], sacc[n], 0, 0, 0);
        }
      }

      // causal mask (only the last tile can straddle the diagonal; uniform branch)
      if (u == nk - 1) {
#pragma unroll
        for (int n = 0; n < 8; n++)
#pragma unroll
          for (int r = 0; r < 4; r++) {
            int key = u * 128 + 16 * n + g4 * 4 + r;
            if (key > qg) sacc[n][r] = -__builtin_inff();
          }
      }
      float vmax = -__builtin_inff();
#pragma unroll
      for (int n = 0; n < 8; n++)
#pragma unroll
        for (int r = 0; r < 4; r++) vmax = fmaxf(vmax, sacc[n][r]);
      vmax = fmaxf(vmax, __shfl_xor(vmax, 16));
      vmax = fmaxf(vmax, __shfl_xor(vmax, 32));
      float mn = fmaxf(m_i, vmax);
      float alpha = exp2f(m_i - mn);
      m_i = mn;

      // O^T rescale BEFORE accumulating this tile (col = q -> lane-local alpha)
#pragma unroll
      for (int c = 0; c < 8; c++)
#pragma unroll
        for (int r = 0; r < 4; r++) o[c][r] *= alpha;

      float ssum = 0.0f;
      u16* Pw = &Ps[wave * 1024];  // 16 q x 64 keys, 16B chunks XOR-swizzled by rsw
#pragma unroll
      for (int half = 0; half < 2; half++) {
        // exp + pack + write this half's 64 keys into the per-wave P buffer
#pragma unroll
        for (int nl = 0; nl < 4; nl++) {
          int n = half * 4 + nl;
          float p0 = exp2f(sacc[n][0] - mn);
          float p1 = exp2f(sacc[n][1] - mn);
          float p2 = exp2f(sacc[n][2] - mn);
          float p3 = exp2f(sacc[n][3] - mn);
          ssum += (p0 + p1) + (p2 + p3);
          ushort4 pk;
          pk.x = f2bf(p0); pk.y = f2bf(p1); pk.z = f2bf(p2); pk.w = f2bf(p3);
          // local key kl = 16*nl + g4*4 + r -> chunk 2*nl + (g4>>1), offset (g4&1)*4
          *(ushort4*)(&Pw[r16 * 64 + ((2 * nl + (g4 >> 1)) ^ rsw) * 8 + (g4 & 1) * 4]) = pk;
        }
        // O^T += V^T * P for this half's keys (global 32-key steps kv = half*2 + ks2)
#pragma unroll
        for (int ks2 = 0; ks2 < 2; ks2++) {
          bf16x8 pf = *(const bf16x8*)(&Pw[r16 * 64 + ((ks2 * 4 + g4) ^ rsw) * 8]);
          int kv = half * 2 + ks2;
#pragma unroll
          for (int c = 0; c < 8; c++) {
            bf16x8 vf = *(const bf16x8*)(&Vs[cur][(c * 16 + r16) * 128 + ((kv * 4 + g4) ^ rsw) * 8]);
            o[c] = __builtin_amdgcn_mfma_f32_16x16x32_bf16(vf, pf, o[c], 0, 0, 0);
          }
        }
      }
      ssum += __shfl_xor(ssum, 16);
      ssum += __shfl_xor(ssum, 32);
      l_i = l_i * alpha + ssum;
      cur ^= 1;
    }

    // epilogue: O^T /= l (lane-local), write [B,S,H,HD] bf16 as packed 8B stores
    float rl = 1.0f / l_i;
    u16* dst = O + ((size_t)(b * 2048 + qg)) * 2048 + h * 128;
#pragma unroll
    for (int c = 0; c < 8; c++) {
      ushort4 pk;
      pk.x = f2bf(o[c][0] * rl);
      pk.y = f2bf(o[c][1] * rl);
      pk.z = f2bf(o[c][2] * rl);
      pk.w = f2bf(o[c][3] * rl);
      *(ushort4*)(dst + c * 16 + g4 * 4) = pk;
    }
  }
}

// ---------------- Output projection GEMM ----------------
// out[m,d] = sum_f Attn[m,f] * Wo[d,f]. M=4096, N=2048, K=2048. fp32 output.
__global__ __launch_bounds__(256) void gemm_out(const u16* __restrict__ A,
                                                const u16* __restrict__ W,
                                                float* __restrict__ out) {
  __shared__ __align__(16) u16 As[128 * 64];
  __shared__ __align__(16) u16 Bs[128 * 64];
  const int tid = threadIdx.x;
  const int lane = tid & 63;
  const int wave = tid >> 6;
  const int wm = (wave >> 1) * 64;
  const int wn = (wave & 1) * 64;
  const int r16 = lane & 15;
  const int g4 = lane >> 4;
  const int rsw = r16 & 7;
  const int bm = blockIdx.x * 128;
  const int bn = blockIdx.y * 128;

  size_t aoff[4], boff[4];
  u16* ldsA[4];
  u16* ldsB[4];
#pragma unroll
  for (int i = 0; i < 4; i++) {
    int row = wave * 32 + i * 8 + (lane >> 3);
    int c = (lane & 7) ^ (row & 7);
    aoff[i] = (size_t)(bm + row) * 2048 + c * 8;
    boff[i] = (size_t)(bn + row) * 2048 + c * 8;
    ldsA[i] = &As[(wave * 4 + i) * 512];
    ldsB[i] = &Bs[(wave * 4 + i) * 512];
  }

  f32x4 acc[4][4];
  f32x4 zero = {0.0f, 0.0f, 0.0f, 0.0f};
#pragma unroll
  for (int m = 0; m < 4; m++)
#pragma unroll
    for (int n = 0; n < 4; n++) acc[m][n] = zero;

  for (int kt = 0; kt < 2048; kt += 64) {
    __syncthreads();
#pragma unroll
    for (int i = 0; i < 4; i++) {
      async_copy16(ldsA[i], A + aoff[i] + kt);
      async_copy16(ldsB[i], W + boff[i] + kt);
    }
    __syncthreads();
#pragma unroll
    for (int ks = 0; ks < 2; ks++) {
      bf16x8 af[4], bfr[4];
#pragma unroll
      for (int m = 0; m < 4; m++)
        af[m] = *(const bf16x8*)(&As[(wm + m * 16 + r16) * 64 + ((ks * 4 + g4) ^ rsw) * 8]);
#pragma unroll
      for (int n = 0; n < 4; n++)
        bfr[n] = *(const bf16x8*)(&Bs[(wn + n * 16 + r16) * 64 + ((ks * 4 + g4) ^ rsw) * 8]);
#pragma unroll
      for (int m = 0; m < 4; m++)
#pragma unroll
        for (int n = 0; n < 4; n++)
          acc[m][n] = __builtin_amdgcn_mfma_f32_16x16x32_bf16(af[m], bfr[n], acc[m][n], 0, 0, 0);
    }
  }

#pragma unroll
  for (int m = 0; m < 4; m++) {
#pragma unroll
    for (int n = 0; n < 4; n++) {
#pragma unroll
      for (int r = 0; r < 4; r++) {
        int row = bm + wm + m * 16 + g4 * 4 + r;
        int col = bn + wn + n * 16 + r16;
        out[(size_t)row * 2048 + col] = acc[m][n][r];
      }
    }
  }
}

extern "C" void kernel_launch(void* const* d_in, const int* in_sizes, int n_in,
                              void* d_out, int out_size, void* d_ws, size_t ws_size,
                              hipStream_t stream) {
  const float* hidden = (const float*)d_in[0];  // [2,2048,2048]
  const float* cosb   = (const float*)d_in[1];  // [2048,128]
  const float* sinb   = (const float*)d_in[2];  // [2048,128]
  const float* w_qkv  = (const float*)d_in[3];  // [3,2048,2048] -> flat [6144,2048]
  const float* w_o    = (const float*)d_in[4];  // [2048,2048]
  float* out = (float*)d_out;                   // [2,2048,2048] fp32

  char* ws = (char*)d_ws;
  u16* Xbf    = (u16*)(ws);                 // 16 MiB
  u16* Wqkvbf = (u16*)(ws + 16777216);      // 24 MiB
  u16* Wobf   = (u16*)(ws + 41943040);      // 8 MiB
  u16* Qb     = (u16*)(ws + 50331648);      // [B,H,S,HD] 16 MiB
  u16* Kb     = (u16*)(ws + 67108864);      // [B,H,S,HD] 16 MiB
  u16* Vt     = (u16*)(ws + 83886080);      // [B,H,HD,S] 16 MiB
  u16* Ob     = (u16*)(ws + 100663296);     // [B,S,H,HD] 16 MiB (end 112 MiB)

  cast_all<<<24576, 256, 0, stream>>>(hidden, w_qkv, w_o, Xbf, Wqkvbf, Wobf);
  gemm_qkv<<<dim3(32, 48), 256, 0, stream>>>(Xbf, Wqkvbf, cosb, sinb, Qb, Kb, Vt);
  flash_attn<<<dim3(8, 32), 512, 0, stream>>>(Qb, Kb, Vt, Ob);
  gemm_out<<<dim3(32, 16), 256, 0, stream>>>(Ob, Wobf, out);
}